// Round 5
// baseline (238.229 us; speedup 1.0000x reference)
//
#include <hip/hip_runtime.h>
#include <hip/hip_bf16.h>

// Problem (fp32 in/out): x[1][16][10][32][64][64], W[4][16][3][3][3][3], b[4]
// out[1][4][10][32][64][64] = softmax_over_channel(conv4d(x,W,pad=1)+b)
//
// MFMA mapping (verified R4): D[m=x][n=(dx,co)] over K=(offset,ci);
// 14 x mfma_f32_16x16x32_bf16 per 16-x tile; dx resolved in LDS epilogue.
#define CIN  16
#define COUT 4
#define TT   10
#define ZZ   32
#define YY   64
#define XX   64

constexpr int SX_CI = TT * ZZ * YY * XX;  // 1310720
constexpr int SX_T  = ZZ * YY * XX;       // 131072
constexpr int SX_Z  = YY * XX;            // 4096
constexpr int WCO   = CIN * 81;           // 1296

// x_t byte strides (bf16, ci innermost: [t][z][y][x][ci])
constexpr int XT_TB = ZZ * YY * XX * CIN * 2;  // 4194304
constexpr int XT_ZB = YY * XX * CIN * 2;       // 131072
constexpr int XT_YB = XX * CIN * 2;            // 2048
constexpr size_t XT_BYTES = (size_t)TT * XT_TB;          // 41,943,040
constexpr size_t TABLE_OFF = XT_BYTES;                   // B-frag table: 14 KB
constexpr size_t ZERO_OFF  = TABLE_OFF + 14 * 1024;      // 2560 B zeroed region
constexpr size_t WS_NEED   = ZERO_OFF + 2560;

typedef short  short8 __attribute__((ext_vector_type(8)));
typedef float  f32x4  __attribute__((ext_vector_type(4)));

__device__ __forceinline__ unsigned short f2bf(float f) {
    union { __hip_bfloat16 h; unsigned short u; } c;
    c.h = __float2bfloat16(f);
    return c.u;
}

// ---- transpose: x (fp32, ci outer) -> x_t (bf16, ci inner). One (t,z,8-y)
// chunk per 256-thread block: 2KB-contiguous reads per channel, 16KB
// contiguous write. LDS stride 513 (odd) => conflict-free. ----
__global__ __launch_bounds__(256) void transpose_x(const float* __restrict__ x,
                                                   char* __restrict__ ws) {
    __shared__ float lds[CIN * 513];
    const int tid = threadIdx.x;
    const int y0 = blockIdx.x * 8, z = blockIdx.y, t = blockIdx.z;
    const size_t base = (size_t)t * SX_T + (size_t)z * SX_Z + (size_t)y0 * XX;
#pragma unroll
    for (int ci = 0; ci < CIN; ++ci) {
        const float2 v = *(const float2*)(x + (size_t)ci * SX_CI + base + tid * 2);
        lds[ci * 513 + tid * 2 + 0] = v.x;
        lds[ci * 513 + tid * 2 + 1] = v.y;
    }
    __syncthreads();
#pragma unroll
    for (int pp = 0; pp < 2; ++pp) {
        const int p = tid * 2 + pp;               // point 0..511 = (y-y0)*64 + x
        unsigned int d[8];
#pragma unroll
        for (int j = 0; j < 8; ++j) {
            const unsigned short lo = f2bf(lds[(2 * j + 0) * 513 + p]);
            const unsigned short hi = f2bf(lds[(2 * j + 1) * 513 + p]);
            d[j] = (unsigned int)lo | ((unsigned int)hi << 16);
        }
        char* dst = ws + ((((size_t)t * ZZ + z) * YY + y0) * XX + p) * 32;
        *(uint4*)(dst + 0)  = make_uint4(d[0], d[1], d[2], d[3]);
        *(uint4*)(dst + 16) = make_uint4(d[4], d[5], d[6], d[7]);
    }
}

// ---- prep: per-lane B fragments (weights) + zero region (verified R4) ----
__global__ void prep_B(const float* __restrict__ W, char* __restrict__ ws) {
    const int g = blockIdx.x * 128 + threadIdx.x;
    if (g < 14 * 64) {
        const int p = g >> 6, L = g & 63;
        const int q = L >> 4, n = L & 15;
        const int co = n & 3, dx = n >> 2;
        const int sel = q >> 1, cilo = (q & 1) * 8;
        const int idx = 2 * p + sel;
        unsigned int d[4];
#pragma unroll
        for (int j = 0; j < 4; ++j) {
            unsigned short u[2];
#pragma unroll
            for (int s = 0; s < 2; ++s) {
                float val = 0.f;
                if (dx < 3 && idx < 27) {
                    const int dt = idx / 9, dz = (idx / 3) % 3, dy = idx % 3;
                    const int ci = cilo + 2 * j + s;
                    val = W[(co * CIN + ci) * 81 + dt * 27 + dz * 9 + dy * 3 + dx];
                }
                u[s] = f2bf(val);
            }
            d[j] = (unsigned int)u[0] | ((unsigned int)u[1] << 16);
        }
        *(uint4*)(ws + TABLE_OFF + (size_t)p * 1024 + (size_t)L * 16) =
            make_uint4(d[0], d[1], d[2], d[3]);
    } else if (g < 14 * 64 + 640) {
        ((unsigned int*)(ws + ZERO_OFF))[g - 14 * 64] = 0u;
    }
}

// row offset for (dt,dz,dy) slot idx at output (t0,z0,y); OOB -> zero region.
// idx is a literal under full inlining => dt/dz/dy const-fold.
__device__ __forceinline__ int row_off(int t0, int z0, int y, int idx) {
    const int dt = idx / 9, dz = (idx / 3) % 3, dy = idx % 3;
    const int t_in = t0 + dt - 1, z_in = z0 + dz - 1, y_in = y + dy - 1;
    const int tc = min(max(t_in, 0), TT - 1);
    const int zc = min(max(z_in, 0), ZZ - 1);
    const int yc = min(max(y_in, 0), YY - 1);
    const bool v = ((unsigned)t_in < TT) && ((unsigned)z_in < ZZ) &&
                   ((unsigned)y_in < YY);
    return v ? (tc * XT_TB + zc * XT_ZB + yc * XT_YB) : (int)ZERO_OFF;
}

#define LROW 21   // LDS row stride (dwords); odd => conflict-free
__global__ __launch_bounds__(256, 3) void conv_mfma(
        const char* __restrict__ ws,
        const float* __restrict__ bias,
        float* __restrict__ out) {
    __shared__ float smem[4 * 66 * LROW];
    const int lane = threadIdx.x;
    const int wid  = __builtin_amdgcn_readfirstlane(threadIdx.y);
    const int yq = blockIdx.x, z0 = blockIdx.y, t0 = blockIdx.z;

    // B fragments: 14 x 8 bf16 in VGPRs (56 VGPRs)
    short8 Bf[14];
#pragma unroll
    for (int p = 0; p < 14; ++p)
        Bf[p] = *(const short8*)(ws + TABLE_OFF + p * 1024 + lane * 16);

    const int voffbase = (lane & 15) * 32 + ((lane >> 4) & 1) * 16;
    float* swave = smem + wid * (66 * LROW);
    if (lane < LROW) {                 // zero pad rows x_in=-1 and x_in=64
        swave[lane] = 0.f;
        swave[65 * LROW + lane] = 0.f;
    }
    const float bi0 = bias[0], bi1 = bias[1], bi2 = bias[2], bi3 = bias[3];

#pragma unroll 1
    for (int r = 0; r < 4; ++r) {
        const int y = yq * 16 + wid * 4 + r;
        // 27 wave-uniform row offsets as NAMED scalars (no array => no scratch);
        // readfirstlane pins them to SGPRs.
#define RO(i) const int o##i = __builtin_amdgcn_readfirstlane(row_off(t0, z0, y, i));
        RO(0)  RO(1)  RO(2)  RO(3)  RO(4)  RO(5)  RO(6)  RO(7)  RO(8)
        RO(9)  RO(10) RO(11) RO(12) RO(13) RO(14) RO(15) RO(16) RO(17)
        RO(18) RO(19) RO(20) RO(21) RO(22) RO(23) RO(24) RO(25) RO(26)
#undef RO
        const int o27 = (int)ZERO_OFF;   // K-pad slot

        f32x4 acc[4];
#pragma unroll
        for (int xt = 0; xt < 4; ++xt) acc[xt] = (f32x4){0.f, 0.f, 0.f, 0.f};

#pragma unroll
        for (int xt = 0; xt < 4; ++xt) {        // 4 independent MFMA chains
            const int vbase = voffbase + xt * 512;
#define STEP(p, ea, eb) { \
            const int rel = (lane & 32) ? (eb) : (ea); \
            const short8 afr = *(const short8*)(ws + (size_t)(unsigned)(rel + vbase)); \
            acc[xt] = __builtin_amdgcn_mfma_f32_16x16x32_bf16(afr, Bf[p], acc[xt], 0, 0, 0); }
            STEP(0,  o0,  o1)  STEP(1,  o2,  o3)  STEP(2,  o4,  o5)
            STEP(3,  o6,  o7)  STEP(4,  o8,  o9)  STEP(5,  o10, o11)
            STEP(6,  o12, o13) STEP(7,  o14, o15) STEP(8,  o16, o17)
            STEP(9,  o18, o19) STEP(10, o20, o21) STEP(11, o22, o23)
            STEP(12, o24, o25) STEP(13, o26, o27)
#undef STEP
        }
        // D -> LDS: row = x_in+1 = xt*16 + quad*4 + reg + 1, col = n
        const int colw = lane & 15;
        const int rowq = (lane >> 4) * 4 + 1;
#pragma unroll
        for (int xt = 0; xt < 4; ++xt)
#pragma unroll
            for (int reg = 0; reg < 4; ++reg)
                swave[(xt * 16 + rowq + reg) * LROW + colw] = acc[xt][reg];

        // epilogue: lane = x_out; gather 3 dx x 4 co, softmax, store
        float lg0 = bi0, lg1 = bi1, lg2 = bi2, lg3 = bi3;
#pragma unroll
        for (int dx = 0; dx < 3; ++dx) {
            const float* sp = swave + (lane + dx) * LROW + dx * 4;
            lg0 += sp[0]; lg1 += sp[1]; lg2 += sp[2]; lg3 += sp[3];
        }
        const float m  = fmaxf(fmaxf(lg0, lg1), fmaxf(lg2, lg3));
        const float e0 = __expf(lg0 - m);
        const float e1 = __expf(lg1 - m);
        const float e2 = __expf(lg2 - m);
        const float e3 = __expf(lg3 - m);
        const float inv = 1.f / (e0 + e1 + e2 + e3);
        float* op = out + (size_t)t0 * SX_T + (size_t)z0 * SX_Z + (size_t)y * XX + lane;
        op[0 * (size_t)SX_CI] = e0 * inv;
        op[1 * (size_t)SX_CI] = e1 * inv;
        op[2 * (size_t)SX_CI] = e2 * inv;
        op[3 * (size_t)SX_CI] = e3 * inv;
    }
}

// ================= fallback (R3 vector kernel) if ws too small =================
__global__ __launch_bounds__(256, 4) void conv4d_softmax_vec(
        const float* __restrict__ x, const float* __restrict__ W,
        const float* __restrict__ b, float* __restrict__ out) {
    const int lane = threadIdx.x;
    const int xg = lane & 15, yl = lane >> 4;
    const int y = blockIdx.x * 16 + threadIdx.y * 4 + yl;
    const int z0 = blockIdx.y, t0 = blockIdx.z, x0 = xg * 4;
    float acc[COUT][4];
#pragma unroll
    for (int c = 0; c < COUT; ++c)
#pragma unroll
        for (int xi = 0; xi < 4; ++xi) acc[c][xi] = 0.f;
    for (int ci = 0; ci < CIN; ++ci) {
        const float* xc = x + (size_t)ci * SX_CI;
        const float* wc = W + ci * 81;
#pragma unroll
        for (int dt = 0; dt < 3; ++dt) {
            const int t_in = t0 + dt - 1;
            const int t_c = min(max(t_in, 0), TT - 1);
            const bool tv = (unsigned)t_in < TT;
#pragma unroll
            for (int dz = 0; dz < 3; ++dz) {
                const int z_in = z0 + dz - 1;
                const int z_c = min(max(z_in, 0), ZZ - 1);
                const bool tzvv = tv && ((unsigned)z_in < ZZ);
                const float* plane = xc + (size_t)t_c * SX_T + (size_t)z_c * SX_Z;
                const float* wb = wc + (dt * 3 + dz) * 9;
#pragma unroll
                for (int e = 0; e < 3; ++e) {
                    const int y_in = y + e - 1;
                    const int y_c = min(max(y_in, 0), YY - 1);
                    const bool v = tzvv && ((unsigned)y_in < YY);
                    float4 f = *(const float4*)(plane + y_c * XX + x0);
                    f.x = v ? f.x : 0.f; f.y = v ? f.y : 0.f;
                    f.z = v ? f.z : 0.f; f.w = v ? f.w : 0.f;
                    float hl = __shfl(f.w, (lane - 1) & 63, 64);
                    hl = (xg == 0) ? 0.f : hl;
                    float hr = __shfl(f.x, (lane + 1) & 63, 64);
                    hr = (xg == 15) ? 0.f : hr;
                    const float win[6] = {hl, f.x, f.y, f.z, f.w, hr};
#pragma unroll
                    for (int co = 0; co < COUT; ++co) {
                        const float* wp = wb + co * WCO + e * 3;
                        const float w0 = wp[0], w1 = wp[1], w2 = wp[2];
#pragma unroll
                        for (int xi = 0; xi < 4; ++xi) {
                            float a = acc[co][xi];
                            a = fmaf(win[xi], w0, a);
                            a = fmaf(win[xi + 1], w1, a);
                            a = fmaf(win[xi + 2], w2, a);
                            acc[co][xi] = a;
                        }
                    }
                }
            }
        }
    }
    const float b0 = b[0], b1 = b[1], b2 = b[2], b3 = b[3];
    float4 rr[COUT];
#pragma unroll
    for (int xi = 0; xi < 4; ++xi) {
        const float a0 = acc[0][xi] + b0, a1 = acc[1][xi] + b1;
        const float a2 = acc[2][xi] + b2, a3 = acc[3][xi] + b3;
        const float m = fmaxf(fmaxf(a0, a1), fmaxf(a2, a3));
        const float e0 = __expf(a0 - m), e1 = __expf(a1 - m);
        const float e2 = __expf(a2 - m), e3 = __expf(a3 - m);
        const float inv = 1.f / (e0 + e1 + e2 + e3);
        ((float*)&rr[0])[xi] = e0 * inv; ((float*)&rr[1])[xi] = e1 * inv;
        ((float*)&rr[2])[xi] = e2 * inv; ((float*)&rr[3])[xi] = e3 * inv;
    }
    float* op = out + (size_t)t0 * SX_T + (size_t)z0 * SX_Z + (size_t)y * XX + x0;
#pragma unroll
    for (int co = 0; co < COUT; ++co)
        *(float4*)(op + (size_t)co * SX_CI) = rr[co];
}

extern "C" void kernel_launch(void* const* d_in, const int* in_sizes, int n_in,
                              void* d_out, int out_size, void* d_ws, size_t ws_size,
                              hipStream_t stream) {
    const float* x = (const float*)d_in[0];
    const float* W = (const float*)d_in[1];
    const float* b = (const float*)d_in[2];
    float* out = (float*)d_out;

    if (ws_size >= WS_NEED) {
        char* ws = (char*)d_ws;
        transpose_x<<<dim3(YY / 8, ZZ, TT), dim3(256), 0, stream>>>(x, ws);
        prep_B<<<dim3(12), dim3(128), 0, stream>>>(W, ws);
        conv_mfma<<<dim3(4, ZZ, TT), dim3(64, 4), 0, stream>>>(ws, b, out);
    } else {
        conv4d_softmax_vec<<<dim3(4, ZZ, TT), dim3(64, 4), 0, stream>>>(x, W, b, out);
    }
}

// Round 6
// 185.604 us; speedup vs baseline: 1.2835x; 1.2835x over previous
//
#include <hip/hip_runtime.h>
#include <hip/hip_bf16.h>

// Problem (fp32 in/out): x[1][16][10][32][64][64], W[4][16][3][3][3][3], b[4]
// out[1][4][10][32][64][64] = softmax_over_channel(conv4d(x,W,pad=1)+b)
//
// R6 structure: pre-transpose x -> x_t[t][z][y][x][ci] bf16 (swizzled rows);
// conv blocks loop 9 (dt,dz) planes, double-buffered global_load_lds staging
// (36KB/plane), 2 MFMAs per (r,xt) per plane, acc[4][4] in registers.
#define CIN  16
#define COUT 4
#define TT   10
#define ZZ   32
#define YY   64
#define XX   64

constexpr int SX_CI = TT * ZZ * YY * XX;  // 1310720
constexpr int SX_T  = ZZ * YY * XX;       // 131072
constexpr int SX_Z  = YY * XX;            // 4096
constexpr int WCO   = CIN * 81;           // 1296

constexpr int XT_TB = ZZ * YY * XX * CIN * 2;  // 4194304
constexpr int XT_ZB = YY * XX * CIN * 2;       // 131072
constexpr int XT_YB = XX * CIN * 2;            // 2048 (one row)
constexpr size_t XT_BYTES = (size_t)TT * XT_TB;    // 41,943,040
constexpr size_t BTAB     = XT_BYTES;              // 9 planes x 2 frags x 1KB
constexpr size_t ZOFF     = BTAB + 9 * 2048;       // 2048B zero row
constexpr size_t WS_NEED  = ZOFF + 2048;

typedef short  short8 __attribute__((ext_vector_type(8)));
typedef float  f32x4  __attribute__((ext_vector_type(4)));

__device__ __forceinline__ unsigned short f2bf(float f) {
    union { __hip_bfloat16 h; unsigned short u; } c;
    c.h = __float2bfloat16(f);
    return c.u;
}
__device__ __forceinline__ unsigned int pk(float a, float b) {
    return (unsigned int)f2bf(a) | ((unsigned int)f2bf(b) << 16);
}
// swizzled byte offset of 16B-chunk c (0..127) within a 2048B row:
// kills the stride-32B 4-way LDS bank conflict on fragment reads.
__device__ __forceinline__ int swz16(int c) { return (c ^ ((c >> 3) & 1)) * 16; }

// ---- transpose v3: lane = x. Each lane gathers 16 ci in registers (reads =
// coalesced 512B float2 rows), writes its own 64B of x_t. No LDS. ----
__global__ __launch_bounds__(256) void transpose_x(const float* __restrict__ x,
                                                   char* __restrict__ ws) {
    const int lane = threadIdx.x & 63;
    const int w    = threadIdx.x >> 6;
    const int yq = blockIdx.x, z = blockIdx.y, t = blockIdx.z;
    const size_t ebase = (size_t)t * SX_T + (size_t)z * SX_Z;
#pragma unroll
    for (int pass = 0; pass < 2; ++pass) {
        const int ypair = yq * 16 + w * 4 + pass * 2;   // rows ypair, ypair+1
        float2 v[16];
#pragma unroll
        for (int ci = 0; ci < 16; ++ci)
            v[ci] = *(const float2*)(x + (size_t)ci * SX_CI + ebase +
                                     (size_t)ypair * XX + lane * 2);
        // lane owns points (2*lane+e): e<..: y = ypair + (lane>>5), x = 2*(lane&31)+e
        const int yy = ypair + (lane >> 5);
        const int xb = 2 * (lane & 31);
        char* rowp = ws + (((size_t)t * ZZ + z) * YY + yy) * 2048;
#pragma unroll
        for (int e = 0; e < 2; ++e) {
            const int xp = xb + e;
#pragma unroll
            for (int hh = 0; hh < 2; ++hh) {
                uint4 d;
                d.x = pk(e ? v[8*hh+0].y : v[8*hh+0].x, e ? v[8*hh+1].y : v[8*hh+1].x);
                d.y = pk(e ? v[8*hh+2].y : v[8*hh+2].x, e ? v[8*hh+3].y : v[8*hh+3].x);
                d.z = pk(e ? v[8*hh+4].y : v[8*hh+4].x, e ? v[8*hh+5].y : v[8*hh+5].x);
                d.w = pk(e ? v[8*hh+6].y : v[8*hh+6].x, e ? v[8*hh+7].y : v[8*hh+7].x);
                *(uint4*)(rowp + swz16(2 * xp + hh)) = d;
            }
        }
    }
}

// ---- prep: B-fragment tables (per plane p=(dt,dz): fragA = K(dy0,dy1)xci,
// fragB = K(dy2)xci zero-padded to K32) + 2KB zero row ----
__global__ void prep_B(const float* __restrict__ W, char* __restrict__ ws) {
    const int g = blockIdx.x * 256 + threadIdx.x;   // [0,1280)
    if (g < 1152) {
        const int p = g >> 7, rem = g & 127, frag = rem >> 6, L = rem & 63;
        const int q = L >> 4, n = L & 15, co = n & 3, dx = n >> 2;
        const int dt = p / 3, dz = p % 3;
        unsigned int d[4];
#pragma unroll
        for (int j = 0; j < 4; ++j) {
            float v0 = 0.f, v1 = 0.f;
            if (dx < 3) {
                if (frag == 0) {                     // k=q*8+j': dy=q>>1, ci=(q&1)*8+j'
                    const int dy = q >> 1;
                    const int ci0 = (q & 1) * 8 + 2 * j;
                    v0 = W[(co * CIN + ci0) * 81 + dt * 27 + dz * 9 + dy * 3 + dx];
                    v1 = W[(co * CIN + ci0 + 1) * 81 + dt * 27 + dz * 9 + dy * 3 + dx];
                } else if (q < 2) {                  // k<16: dy=2, ci=k; k>=16: zero
                    const int ci0 = q * 8 + 2 * j;
                    v0 = W[(co * CIN + ci0) * 81 + dt * 27 + dz * 9 + 6 + dx];
                    v1 = W[(co * CIN + ci0 + 1) * 81 + dt * 27 + dz * 9 + 6 + dx];
                }
            }
            d[j] = pk(v0, v1);
        }
        *(uint4*)(ws + BTAB + (size_t)p * 2048 + frag * 1024 + (size_t)L * 16) =
            make_uint4(d[0], d[1], d[2], d[3]);
    } else if (g < 1280) {
        *(uint4*)(ws + ZOFF + (size_t)(g - 1152) * 16) = make_uint4(0, 0, 0, 0);
    }
}

#define GL16(SRC, DST) __builtin_amdgcn_global_load_lds( \
    (const __attribute__((address_space(1))) unsigned int*)(SRC), \
    (__attribute__((address_space(3))) unsigned int*)(DST), 16, 0, 0)

#define LROW 21
__global__ __launch_bounds__(256, 3) void conv_mfma(
        const char* __restrict__ ws,
        const float* __restrict__ bias,
        float* __restrict__ out) {
    __shared__ char smem[2 * 18 * 2048];   // 73,728 B: two 18-row plane buffers
    const int lane = threadIdx.x;
    const int wid  = __builtin_amdgcn_readfirstlane(threadIdx.y);
    const int yq = blockIdx.x, z0 = blockIdx.y, t0 = blockIdx.z;
    const int y0 = yq * 16;
    const int m = lane & 15, q = lane >> 4, h = q & 1, dyA = q >> 1;
    const int e2 = 2 * m + h;
    const int wid4 = wid * 4;
    const bool qlo = q < 2;

    f32x4 acc[4][4];
#pragma unroll
    for (int r = 0; r < 4; ++r)
#pragma unroll
        for (int xt = 0; xt < 4; ++xt) acc[r][xt] = (f32x4){0.f, 0.f, 0.f, 0.f};

// Stage plane P (18 rows x 2048B, contiguous in x_t) into buffer P&1.
// Wave w, iter k stages half-row: row=(w+4k)>>1, half=(w+4k)&1 — wave-uniform
// base + lane*16 as global_load_lds requires. OOB rows/planes -> zero row.
#define STAGE(P) { \
    const int dtS = (P) / 3, dzS = (P) % 3; \
    const int t_in = t0 + dtS - 1, z_in = z0 + dzS - 1; \
    const bool pv = ((unsigned)t_in < TT) && ((unsigned)z_in < ZZ); \
    const int pbase = pv ? (t_in * XT_TB + z_in * XT_ZB) : 0; \
    char* bbS = smem + ((P) & 1) * 36864; \
    _Pragma("unroll") \
    for (int k = 0; k < 9; ++k) { \
        const int rw = (wid + 4 * k) >> 1; \
        const int hf = ((wid + 4 * k) & 1) * 1024; \
        const int y_in = y0 - 1 + rw; \
        const bool rv = pv && ((unsigned)y_in < YY); \
        const char* srcS = ws + (rv ? (size_t)(pbase + y_in * XT_YB) : ZOFF) \
                              + hf + lane * 16; \
        GL16(srcS, bbS + rw * 2048 + hf + lane * 16); \
    } }

// Compute plane P from buffer P&1: per (r,xt) two K=32 MFMAs.
#define COMPUTE(P) { \
    const char* bbC = smem + ((P) & 1) * 36864; \
    const short8 BfA = *(const short8*)(ws + BTAB + (P) * 2048 + lane * 16); \
    const short8 BfB = *(const short8*)(ws + BTAB + (P) * 2048 + 1024 + lane * 16); \
    _Pragma("unroll") \
    for (int r = 0; r < 4; ++r) { \
        _Pragma("unroll") \
        for (int xt = 0; xt < 4; ++xt) { \
            const int sw = swz16(32 * xt + e2); \
            const short8 fa = *(const short8*)(bbC + (wid4 + r + dyA) * 2048 + sw); \
            short8 fb = *(const short8*)(bbC + (wid4 + r + 2) * 2048 + sw); \
            fb = qlo ? fb : (short8)0; \
            acc[r][xt] = __builtin_amdgcn_mfma_f32_16x16x32_bf16(fa, BfA, acc[r][xt], 0, 0, 0); \
            acc[r][xt] = __builtin_amdgcn_mfma_f32_16x16x32_bf16(fb, BfB, acc[r][xt], 0, 0, 0); \
        } } }

    STAGE(0)
    STAGE(1) __syncthreads(); COMPUTE(0) __syncthreads();
    STAGE(2) __syncthreads(); COMPUTE(1) __syncthreads();
    STAGE(3) __syncthreads(); COMPUTE(2) __syncthreads();
    STAGE(4) __syncthreads(); COMPUTE(3) __syncthreads();
    STAGE(5) __syncthreads(); COMPUTE(4) __syncthreads();
    STAGE(6) __syncthreads(); COMPUTE(5) __syncthreads();
    STAGE(7) __syncthreads(); COMPUTE(6) __syncthreads();
    STAGE(8) __syncthreads(); COMPUTE(7) __syncthreads();
    COMPUTE(8)
    __syncthreads();   // staging buffers dead; alias epilogue region
#undef STAGE
#undef COMPUTE

    const float bi0 = bias[0], bi1 = bias[1], bi2 = bias[2], bi3 = bias[3];
    float* swave = (float*)smem + wid * (66 * LROW);
    if (lane < LROW) {                 // zero pad rows x_in=-1 and x_in=64
        swave[lane] = 0.f;
        swave[65 * LROW + lane] = 0.f;
    }
    const int colw = lane & 15;
    const int rowq = (lane >> 4) * 4 + 1;
#pragma unroll
    for (int r = 0; r < 4; ++r) {
#pragma unroll
        for (int xt = 0; xt < 4; ++xt)
#pragma unroll
            for (int reg = 0; reg < 4; ++reg)
                swave[(xt * 16 + rowq + reg) * LROW + colw] = acc[r][xt][reg];
        float lg0 = bi0, lg1 = bi1, lg2 = bi2, lg3 = bi3;
#pragma unroll
        for (int dx = 0; dx < 3; ++dx) {
            const float* sp = swave + (lane + dx) * LROW + dx * 4;
            lg0 += sp[0]; lg1 += sp[1]; lg2 += sp[2]; lg3 += sp[3];
        }
        const float mx = fmaxf(fmaxf(lg0, lg1), fmaxf(lg2, lg3));
        const float e0 = __expf(lg0 - mx);
        const float e1 = __expf(lg1 - mx);
        const float e2v = __expf(lg2 - mx);
        const float e3 = __expf(lg3 - mx);
        const float inv = 1.f / (e0 + e1 + e2v + e3);
        const int y = y0 + wid4 + r;
        float* op = out + (size_t)t0 * SX_T + (size_t)z0 * SX_Z + (size_t)y * XX + lane;
        op[0 * (size_t)SX_CI] = e0 * inv;
        op[1 * (size_t)SX_CI] = e1 * inv;
        op[2 * (size_t)SX_CI] = e2v * inv;
        op[3 * (size_t)SX_CI] = e3 * inv;
    }
}

// ================= fallback (R3 vector kernel) if ws too small =================
__global__ __launch_bounds__(256, 4) void conv4d_softmax_vec(
        const float* __restrict__ x, const float* __restrict__ W,
        const float* __restrict__ b, float* __restrict__ out) {
    const int lane = threadIdx.x;
    const int xg = lane & 15, yl = lane >> 4;
    const int y = blockIdx.x * 16 + threadIdx.y * 4 + yl;
    const int z0 = blockIdx.y, t0 = blockIdx.z, x0 = xg * 4;
    float acc[COUT][4];
#pragma unroll
    for (int c = 0; c < COUT; ++c)
#pragma unroll
        for (int xi = 0; xi < 4; ++xi) acc[c][xi] = 0.f;
    for (int ci = 0; ci < CIN; ++ci) {
        const float* xc = x + (size_t)ci * SX_CI;
        const float* wc = W + ci * 81;
#pragma unroll
        for (int dt = 0; dt < 3; ++dt) {
            const int t_in = t0 + dt - 1;
            const int t_c = min(max(t_in, 0), TT - 1);
            const bool tv = (unsigned)t_in < TT;
#pragma unroll
            for (int dz = 0; dz < 3; ++dz) {
                const int z_in = z0 + dz - 1;
                const int z_c = min(max(z_in, 0), ZZ - 1);
                const bool tzvv = tv && ((unsigned)z_in < ZZ);
                const float* plane = xc + (size_t)t_c * SX_T + (size_t)z_c * SX_Z;
                const float* wb = wc + (dt * 3 + dz) * 9;
#pragma unroll
                for (int e = 0; e < 3; ++e) {
                    const int y_in = y + e - 1;
                    const int y_c = min(max(y_in, 0), YY - 1);
                    const bool v = tzvv && ((unsigned)y_in < YY);
                    float4 f = *(const float4*)(plane + y_c * XX + x0);
                    f.x = v ? f.x : 0.f; f.y = v ? f.y : 0.f;
                    f.z = v ? f.z : 0.f; f.w = v ? f.w : 0.f;
                    float hl = __shfl(f.w, (lane - 1) & 63, 64);
                    hl = (xg == 0) ? 0.f : hl;
                    float hr = __shfl(f.x, (lane + 1) & 63, 64);
                    hr = (xg == 15) ? 0.f : hr;
                    const float win[6] = {hl, f.x, f.y, f.z, f.w, hr};
#pragma unroll
                    for (int co = 0; co < COUT; ++co) {
                        const float* wp = wb + co * WCO + e * 3;
                        const float w0 = wp[0], w1 = wp[1], w2 = wp[2];
#pragma unroll
                        for (int xi = 0; xi < 4; ++xi) {
                            float a = acc[co][xi];
                            a = fmaf(win[xi], w0, a);
                            a = fmaf(win[xi + 1], w1, a);
                            a = fmaf(win[xi + 2], w2, a);
                            acc[co][xi] = a;
                        }
                    }
                }
            }
        }
    }
    const float b0 = b[0], b1 = b[1], b2 = b[2], b3 = b[3];
    float4 rr[COUT];
#pragma unroll
    for (int xi = 0; xi < 4; ++xi) {
        const float a0 = acc[0][xi] + b0, a1 = acc[1][xi] + b1;
        const float a2 = acc[2][xi] + b2, a3 = acc[3][xi] + b3;
        const float mm = fmaxf(fmaxf(a0, a1), fmaxf(a2, a3));
        const float e0 = __expf(a0 - mm), e1 = __expf(a1 - mm);
        const float e2 = __expf(a2 - mm), e3 = __expf(a3 - mm);
        const float inv = 1.f / (e0 + e1 + e2 + e3);
        ((float*)&rr[0])[xi] = e0 * inv; ((float*)&rr[1])[xi] = e1 * inv;
        ((float*)&rr[2])[xi] = e2 * inv; ((float*)&rr[3])[xi] = e3 * inv;
    }
    float* op = out + (size_t)t0 * SX_T + (size_t)z0 * SX_Z + (size_t)y * XX + x0;
#pragma unroll
    for (int co = 0; co < COUT; ++co)
        *(float4*)(op + (size_t)co * SX_CI) = rr[co];
}

extern "C" void kernel_launch(void* const* d_in, const int* in_sizes, int n_in,
                              void* d_out, int out_size, void* d_ws, size_t ws_size,
                              hipStream_t stream) {
    const float* x = (const float*)d_in[0];
    const float* W = (const float*)d_in[1];
    const float* b = (const float*)d_in[2];
    float* out = (float*)d_out;

    if (ws_size >= WS_NEED) {
        char* ws = (char*)d_ws;
        transpose_x<<<dim3(4, ZZ, TT), dim3(256), 0, stream>>>(x, ws);
        prep_B<<<dim3(5), dim3(256), 0, stream>>>(W, ws);
        conv_mfma<<<dim3(4, ZZ, TT), dim3(64, 4), 0, stream>>>(ws, b, out);
    } else {
        conv4d_softmax_vec<<<dim3(4, ZZ, TT), dim3(64, 4), 0, stream>>>(x, W, b, out);
    }
}

// Round 7
// 184.667 us; speedup vs baseline: 1.2900x; 1.0051x over previous
//
#include <hip/hip_runtime.h>
#include <hip/hip_bf16.h>

// Problem (fp32 in/out): x[1][16][10][32][64][64], W[4][16][3][3][3][3], b[4]
// out[1][4][10][32][64][64] = softmax_over_channel(conv4d(x,W,pad=1)+b)
//
// R7: x_t[t][z][y][x][ci] bf16 (plain layout). conv: 9-plane K-loop,
// single-buffer 36KB LDS staging (global_load_lds w16), 4 blocks/CU,
// 2 MFMAs (16x16x32) per (r,xt) per plane; fragB K-padded with zeros in B so
// A's k>=16 lanes need no masking. Transpose: LDS-tiled, both sides coalesced.
#define CIN  16
#define COUT 4
#define TT   10
#define ZZ   32
#define YY   64
#define XX   64

constexpr int SX_CI = TT * ZZ * YY * XX;  // 1310720
constexpr int SX_T  = ZZ * YY * XX;       // 131072
constexpr int SX_Z  = YY * XX;            // 4096
constexpr int WCO   = CIN * 81;           // 1296

constexpr int XT_TB = ZZ * YY * XX * CIN * 2;  // 4194304
constexpr int XT_ZB = YY * XX * CIN * 2;       // 131072
constexpr int XT_YB = XX * CIN * 2;            // 2048 (one row)
constexpr size_t XT_BYTES = (size_t)TT * XT_TB;    // 41,943,040
constexpr size_t BTAB     = XT_BYTES;              // 9 planes x 2 frags x 1KB
constexpr size_t ZOFF     = BTAB + 9 * 2048;       // 2048B zero row
constexpr size_t WS_NEED  = ZOFF + 2048;

typedef short  short8 __attribute__((ext_vector_type(8)));
typedef float  f32x4  __attribute__((ext_vector_type(4)));

__device__ __forceinline__ unsigned short f2bf(float f) {
    union { __hip_bfloat16 h; unsigned short u; } c;
    c.h = __float2bfloat16(f);
    return c.u;
}
__device__ __forceinline__ unsigned int pk(float a, float b) {
    return (unsigned int)f2bf(a) | ((unsigned int)f2bf(b) << 16);
}

// ---- transpose v4: LDS-tiled. Block = (t,z,16y). Reads 1KB/instr coalesced;
// LDS x-stride 36B (9 banks -> 2-way max); stores 1KB/instr contiguous. ----
#define TXS 36            // x-stride in LDS tile (bytes)
#define TYS (64 * TXS)    // y-stride: 2304B
__global__ __launch_bounds__(256) void transpose_x(const float* __restrict__ x,
                                                   char* __restrict__ ws) {
    __shared__ char lds[16 * TYS];   // 36,864 B
    const int lane = threadIdx.x & 63;
    const int w    = threadIdx.x >> 6;
    const int yq = blockIdx.x, z = blockIdx.y, t = blockIdx.z;
    const int y0 = yq * 16;
    const int rl = w * 4 + (lane >> 4);          // local row 0..15
    const int x0 = (lane & 15) * 4;
    const size_t gbase = (size_t)t * SX_T + (size_t)z * SX_Z +
                         (size_t)(y0 + rl) * XX + x0;
#pragma unroll
    for (int cp = 0; cp < 8; ++cp) {             // ci pair (2cp, 2cp+1)
        const float4 f0 = *(const float4*)(x + (size_t)(2 * cp + 0) * SX_CI + gbase);
        const float4 f1 = *(const float4*)(x + (size_t)(2 * cp + 1) * SX_CI + gbase);
        char* p = lds + rl * TYS + x0 * TXS + cp * 4;
        *(unsigned int*)(p + 0 * TXS) = pk(f0.x, f1.x);
        *(unsigned int*)(p + 1 * TXS) = pk(f0.y, f1.y);
        *(unsigned int*)(p + 2 * TXS) = pk(f0.z, f1.z);
        *(unsigned int*)(p + 3 * TXS) = pk(f0.w, f1.w);
    }
    __syncthreads();
#pragma unroll
    for (int s = 0; s < 4; ++s) {                // 4 rows per wave
        const int r2 = w * 4 + s;
        char* rowp = ws + (((size_t)t * ZZ + z) * YY + (y0 + r2)) * 2048;
#pragma unroll
        for (int half = 0; half < 2; ++half) {
            const int c = half * 64 + lane;      // chunk 0..127 = (x<<1)|cihalf
            const uint4 d = *(const uint4*)(lds + r2 * TYS + (c >> 1) * TXS +
                                            (c & 1) * 16);
            *(uint4*)(rowp + c * 16) = d;
        }
    }
}

// ---- prep: B-fragment tables (plane p=(dt,dz): fragA = K(dy0,dy1)xci,
// fragB = K(dy2)xci zero-padded to K32) + 2KB zero row ----
__global__ void prep_B(const float* __restrict__ W, char* __restrict__ ws) {
    const int g = blockIdx.x * 256 + threadIdx.x;   // [0,1280)
    if (g < 1152) {
        const int p = g >> 7, rem = g & 127, frag = rem >> 6, L = rem & 63;
        const int q = L >> 4, n = L & 15, co = n & 3, dx = n >> 2;
        const int dt = p / 3, dz = p % 3;
        unsigned int d[4];
#pragma unroll
        for (int j = 0; j < 4; ++j) {
            float v0 = 0.f, v1 = 0.f;
            if (dx < 3) {
                if (frag == 0) {                 // k=q*8+j': dy=q>>1, ci=(q&1)*8+j'
                    const int dy = q >> 1;
                    const int ci0 = (q & 1) * 8 + 2 * j;
                    v0 = W[(co * CIN + ci0) * 81 + dt * 27 + dz * 9 + dy * 3 + dx];
                    v1 = W[(co * CIN + ci0 + 1) * 81 + dt * 27 + dz * 9 + dy * 3 + dx];
                } else if (q < 2) {              // k<16: dy=2; k>=16: zero
                    const int ci0 = q * 8 + 2 * j;
                    v0 = W[(co * CIN + ci0) * 81 + dt * 27 + dz * 9 + 6 + dx];
                    v1 = W[(co * CIN + ci0 + 1) * 81 + dt * 27 + dz * 9 + 6 + dx];
                }
            }
            d[j] = pk(v0, v1);
        }
        *(uint4*)(ws + BTAB + (size_t)p * 2048 + frag * 1024 + (size_t)L * 16) =
            make_uint4(d[0], d[1], d[2], d[3]);
    } else if (g < 1280) {
        *(uint4*)(ws + ZOFF + (size_t)(g - 1152) * 16) = make_uint4(0, 0, 0, 0);
    }
}

#define GL16(SRC, DST) __builtin_amdgcn_global_load_lds( \
    (const __attribute__((address_space(1))) unsigned int*)(SRC), \
    (__attribute__((address_space(3))) unsigned int*)(DST), 16, 0, 0)

#define LROW 21
__global__ __launch_bounds__(256, 4) void conv_mfma(
        const char* __restrict__ ws,
        const float* __restrict__ bias,
        float* __restrict__ out) {
    __shared__ char smem[18 * 2048];   // 36,864 B: one plane buffer (4 blocks/CU)
    const int lane = threadIdx.x;
    const int wid  = __builtin_amdgcn_readfirstlane(threadIdx.y);
    const int yq = blockIdx.x, z0 = blockIdx.y, t0 = blockIdx.z;
    const int y0 = yq * 16;
    const int m = lane & 15, q = lane >> 4, h = q & 1, dyA = q >> 1;
    const int e2 = 2 * m + h;
    const int wid4 = wid * 4;

    f32x4 acc[4][4];
#pragma unroll
    for (int r = 0; r < 4; ++r)
#pragma unroll
        for (int xt = 0; xt < 4; ++xt) acc[r][xt] = (f32x4){0.f, 0.f, 0.f, 0.f};

// Stage plane P (18 rows x 2048B contiguous in x_t) into smem.
// Wave w, iter k stages half-row rw=(w+4k)>>1, half=(w+4k)&1: wave-uniform
// base + lane*16 (global_load_lds constraint). OOB rows/planes -> zero row.
#define STAGE(P) { \
    const int dtS = (P) / 3, dzS = (P) % 3; \
    const int t_in = t0 + dtS - 1, z_in = z0 + dzS - 1; \
    const bool pv = ((unsigned)t_in < TT) && ((unsigned)z_in < ZZ); \
    const int pbase = pv ? (t_in * XT_TB + z_in * XT_ZB) : 0; \
    _Pragma("unroll") \
    for (int k = 0; k < 9; ++k) { \
        const int rw = (wid + 4 * k) >> 1; \
        const int hf = ((wid + 4 * k) & 1) * 1024; \
        const int y_in = y0 - 1 + rw; \
        const bool rv = pv && ((unsigned)y_in < YY); \
        const char* srcS = ws + (rv ? (size_t)(pbase + y_in * XT_YB) : ZOFF) \
                              + hf + lane * 16; \
        GL16(srcS, smem + rw * 2048 + hf + lane * 16); \
    } }

// Compute plane P: per (r,xt) two K=32 MFMAs. fragB's k>=16 is zero IN B, so
// fb needs no lane masking (A garbage * 0 = 0).
#define COMPUTE(P) { \
    const short8 BfA = *(const short8*)(ws + BTAB + (P) * 2048 + lane * 16); \
    const short8 BfB = *(const short8*)(ws + BTAB + (P) * 2048 + 1024 + lane * 16); \
    _Pragma("unroll") \
    for (int r = 0; r < 4; ++r) { \
        _Pragma("unroll") \
        for (int xt = 0; xt < 4; ++xt) { \
            const int sw = (32 * xt + e2) * 16; \
            const short8 fa = *(const short8*)(smem + (wid4 + r + dyA) * 2048 + sw); \
            const short8 fb = *(const short8*)(smem + (wid4 + r + 2) * 2048 + sw); \
            acc[r][xt] = __builtin_amdgcn_mfma_f32_16x16x32_bf16(fa, BfA, acc[r][xt], 0, 0, 0); \
            acc[r][xt] = __builtin_amdgcn_mfma_f32_16x16x32_bf16(fb, BfB, acc[r][xt], 0, 0, 0); \
        } } }

    STAGE(0) __syncthreads(); COMPUTE(0) __syncthreads();
    STAGE(1) __syncthreads(); COMPUTE(1) __syncthreads();
    STAGE(2) __syncthreads(); COMPUTE(2) __syncthreads();
    STAGE(3) __syncthreads(); COMPUTE(3) __syncthreads();
    STAGE(4) __syncthreads(); COMPUTE(4) __syncthreads();
    STAGE(5) __syncthreads(); COMPUTE(5) __syncthreads();
    STAGE(6) __syncthreads(); COMPUTE(6) __syncthreads();
    STAGE(7) __syncthreads(); COMPUTE(7) __syncthreads();
    STAGE(8) __syncthreads(); COMPUTE(8) __syncthreads();
#undef STAGE
#undef COMPUTE

    const float bi0 = bias[0], bi1 = bias[1], bi2 = bias[2], bi3 = bias[3];
    float* swave = (float*)smem + wid * (66 * LROW);   // aliases dead staging buf
    if (lane < LROW) {                 // zero pad rows x_in=-1 and x_in=64
        swave[lane] = 0.f;
        swave[65 * LROW + lane] = 0.f;
    }
    const int colw = lane & 15;
    const int rowq = (lane >> 4) * 4 + 1;
#pragma unroll
    for (int r = 0; r < 4; ++r) {
#pragma unroll
        for (int xt = 0; xt < 4; ++xt)
#pragma unroll
            for (int reg = 0; reg < 4; ++reg)
                swave[(xt * 16 + rowq + reg) * LROW + colw] = acc[r][xt][reg];
        float lg0 = bi0, lg1 = bi1, lg2 = bi2, lg3 = bi3;
#pragma unroll
        for (int dx = 0; dx < 3; ++dx) {
            const float* sp = swave + (lane + dx) * LROW + dx * 4;
            lg0 += sp[0]; lg1 += sp[1]; lg2 += sp[2]; lg3 += sp[3];
        }
        const float mx = fmaxf(fmaxf(lg0, lg1), fmaxf(lg2, lg3));
        const float e0 = __expf(lg0 - mx);
        const float e1 = __expf(lg1 - mx);
        const float e2v = __expf(lg2 - mx);
        const float e3 = __expf(lg3 - mx);
        const float inv = 1.f / (e0 + e1 + e2v + e3);
        const int y = y0 + wid4 + r;
        float* op = out + (size_t)t0 * SX_T + (size_t)z0 * SX_Z + (size_t)y * XX + lane;
        op[0 * (size_t)SX_CI] = e0 * inv;
        op[1 * (size_t)SX_CI] = e1 * inv;
        op[2 * (size_t)SX_CI] = e2v * inv;
        op[3 * (size_t)SX_CI] = e3 * inv;
    }
}

// ================= fallback (R3 vector kernel) if ws too small =================
__global__ __launch_bounds__(256, 4) void conv4d_softmax_vec(
        const float* __restrict__ x, const float* __restrict__ W,
        const float* __restrict__ b, float* __restrict__ out) {
    const int lane = threadIdx.x;
    const int xg = lane & 15, yl = lane >> 4;
    const int y = blockIdx.x * 16 + threadIdx.y * 4 + yl;
    const int z0 = blockIdx.y, t0 = blockIdx.z, x0 = xg * 4;
    float acc[COUT][4];
#pragma unroll
    for (int c = 0; c < COUT; ++c)
#pragma unroll
        for (int xi = 0; xi < 4; ++xi) acc[c][xi] = 0.f;
    for (int ci = 0; ci < CIN; ++ci) {
        const float* xc = x + (size_t)ci * SX_CI;
        const float* wc = W + ci * 81;
#pragma unroll
        for (int dt = 0; dt < 3; ++dt) {
            const int t_in = t0 + dt - 1;
            const int t_c = min(max(t_in, 0), TT - 1);
            const bool tv = (unsigned)t_in < TT;
#pragma unroll
            for (int dz = 0; dz < 3; ++dz) {
                const int z_in = z0 + dz - 1;
                const int z_c = min(max(z_in, 0), ZZ - 1);
                const bool tzvv = tv && ((unsigned)z_in < ZZ);
                const float* plane = xc + (size_t)t_c * SX_T + (size_t)z_c * SX_Z;
                const float* wb = wc + (dt * 3 + dz) * 9;
#pragma unroll
                for (int e = 0; e < 3; ++e) {
                    const int y_in = y + e - 1;
                    const int y_c = min(max(y_in, 0), YY - 1);
                    const bool v = tzvv && ((unsigned)y_in < YY);
                    float4 f = *(const float4*)(plane + y_c * XX + x0);
                    f.x = v ? f.x : 0.f; f.y = v ? f.y : 0.f;
                    f.z = v ? f.z : 0.f; f.w = v ? f.w : 0.f;
                    float hl = __shfl(f.w, (lane - 1) & 63, 64);
                    hl = (xg == 0) ? 0.f : hl;
                    float hr = __shfl(f.x, (lane + 1) & 63, 64);
                    hr = (xg == 15) ? 0.f : hr;
                    const float win[6] = {hl, f.x, f.y, f.z, f.w, hr};
#pragma unroll
                    for (int co = 0; co < COUT; ++co) {
                        const float* wp = wb + co * WCO + e * 3;
                        const float w0 = wp[0], w1 = wp[1], w2 = wp[2];
#pragma unroll
                        for (int xi = 0; xi < 4; ++xi) {
                            float a = acc[co][xi];
                            a = fmaf(win[xi], w0, a);
                            a = fmaf(win[xi + 1], w1, a);
                            a = fmaf(win[xi + 2], w2, a);
                            acc[co][xi] = a;
                        }
                    }
                }
            }
        }
    }
    const float b0 = b[0], b1 = b[1], b2 = b[2], b3 = b[3];
    float4 rr[COUT];
#pragma unroll
    for (int xi = 0; xi < 4; ++xi) {
        const float a0 = acc[0][xi] + b0, a1 = acc[1][xi] + b1;
        const float a2 = acc[2][xi] + b2, a3 = acc[3][xi] + b3;
        const float mm = fmaxf(fmaxf(a0, a1), fmaxf(a2, a3));
        const float e0 = __expf(a0 - mm), e1 = __expf(a1 - mm);
        const float e2 = __expf(a2 - mm), e3 = __expf(a3 - mm);
        const float inv = 1.f / (e0 + e1 + e2 + e3);
        ((float*)&rr[0])[xi] = e0 * inv; ((float*)&rr[1])[xi] = e1 * inv;
        ((float*)&rr[2])[xi] = e2 * inv; ((float*)&rr[3])[xi] = e3 * inv;
    }
    float* op = out + (size_t)t0 * SX_T + (size_t)z0 * SX_Z + (size_t)y * XX + x0;
#pragma unroll
    for (int co = 0; co < COUT; ++co)
        *(float4*)(op + (size_t)co * SX_CI) = rr[co];
}

extern "C" void kernel_launch(void* const* d_in, const int* in_sizes, int n_in,
                              void* d_out, int out_size, void* d_ws, size_t ws_size,
                              hipStream_t stream) {
    const float* x = (const float*)d_in[0];
    const float* W = (const float*)d_in[1];
    const float* b = (const float*)d_in[2];
    float* out = (float*)d_out;

    if (ws_size >= WS_NEED) {
        char* ws = (char*)d_ws;
        transpose_x<<<dim3(4, ZZ, TT), dim3(256), 0, stream>>>(x, ws);
        prep_B<<<dim3(5), dim3(256), 0, stream>>>(W, ws);
        conv_mfma<<<dim3(4, ZZ, TT), dim3(64, 4), 0, stream>>>(ws, b, out);
    } else {
        conv4d_softmax_vec<<<dim3(4, ZZ, TT), dim3(64, 4), 0, stream>>>(x, W, b, out);
    }
}

// Round 8
// 171.560 us; speedup vs baseline: 1.3886x; 1.0764x over previous
//
#include <hip/hip_runtime.h>
#include <hip/hip_bf16.h>

// Problem (fp32 in/out): x[1][16][10][32][64][64], W[4][16][3][3][3][3], b[4]
// out[1][4][10][32][64][64] = softmax_over_channel(conv4d(x,W,pad=1)+b)
//
// R8: x_t[t][z][y][x][ci] bf16. conv: 9-plane K-loop, TRUE double-buffered
// LDS staging (stage P+1 issued BEFORE compute P, one barrier per plane so
// loads fly under MFMAs), XCD-swizzled grid for L2 locality.
#define CIN  16
#define COUT 4
#define TT   10
#define ZZ   32
#define YY   64
#define XX   64

constexpr int SX_CI = TT * ZZ * YY * XX;  // 1310720
constexpr int SX_T  = ZZ * YY * XX;       // 131072
constexpr int SX_Z  = YY * XX;            // 4096
constexpr int WCO   = CIN * 81;           // 1296

constexpr int XT_TB = ZZ * YY * XX * CIN * 2;  // 4194304
constexpr int XT_ZB = YY * XX * CIN * 2;       // 131072
constexpr int XT_YB = XX * CIN * 2;            // 2048 (one row)
constexpr size_t XT_BYTES = (size_t)TT * XT_TB;    // 41,943,040
constexpr size_t BTAB     = XT_BYTES;              // 9 planes x 2 frags x 1KB
constexpr size_t ZOFF     = BTAB + 9 * 2048;       // 2048B zero row
constexpr size_t WS_NEED  = ZOFF + 2048;

typedef short  short8 __attribute__((ext_vector_type(8)));
typedef float  f32x4  __attribute__((ext_vector_type(4)));

__device__ __forceinline__ unsigned short f2bf(float f) {
    union { __hip_bfloat16 h; unsigned short u; } c;
    c.h = __float2bfloat16(f);
    return c.u;
}
__device__ __forceinline__ unsigned int pk(float a, float b) {
    return (unsigned int)f2bf(a) | ((unsigned int)f2bf(b) << 16);
}

// ---- transpose v4 (R7, ~fine): LDS-tiled, both global sides coalesced ----
#define TXS 36
#define TYS (64 * TXS)
__global__ __launch_bounds__(256) void transpose_x(const float* __restrict__ x,
                                                   char* __restrict__ ws) {
    __shared__ char lds[16 * TYS];   // 36,864 B
    const int lane = threadIdx.x & 63;
    const int w    = threadIdx.x >> 6;
    const int yq = blockIdx.x, z = blockIdx.y, t = blockIdx.z;
    const int y0 = yq * 16;
    const int rl = w * 4 + (lane >> 4);
    const int x0 = (lane & 15) * 4;
    const size_t gbase = (size_t)t * SX_T + (size_t)z * SX_Z +
                         (size_t)(y0 + rl) * XX + x0;
#pragma unroll
    for (int cp = 0; cp < 8; ++cp) {
        const float4 f0 = *(const float4*)(x + (size_t)(2 * cp + 0) * SX_CI + gbase);
        const float4 f1 = *(const float4*)(x + (size_t)(2 * cp + 1) * SX_CI + gbase);
        char* p = lds + rl * TYS + x0 * TXS + cp * 4;
        *(unsigned int*)(p + 0 * TXS) = pk(f0.x, f1.x);
        *(unsigned int*)(p + 1 * TXS) = pk(f0.y, f1.y);
        *(unsigned int*)(p + 2 * TXS) = pk(f0.z, f1.z);
        *(unsigned int*)(p + 3 * TXS) = pk(f0.w, f1.w);
    }
    __syncthreads();
#pragma unroll
    for (int s = 0; s < 4; ++s) {
        const int r2 = w * 4 + s;
        char* rowp = ws + (((size_t)t * ZZ + z) * YY + (y0 + r2)) * 2048;
#pragma unroll
        for (int half = 0; half < 2; ++half) {
            const int c = half * 64 + lane;
            const uint4 d = *(const uint4*)(lds + r2 * TYS + (c >> 1) * TXS +
                                            (c & 1) * 16);
            *(uint4*)(rowp + c * 16) = d;
        }
    }
}

// ---- prep: B-fragment tables + zero row (verified R7) ----
__global__ void prep_B(const float* __restrict__ W, char* __restrict__ ws) {
    const int g = blockIdx.x * 256 + threadIdx.x;
    if (g < 1152) {
        const int p = g >> 7, rem = g & 127, frag = rem >> 6, L = rem & 63;
        const int q = L >> 4, n = L & 15, co = n & 3, dx = n >> 2;
        const int dt = p / 3, dz = p % 3;
        unsigned int d[4];
#pragma unroll
        for (int j = 0; j < 4; ++j) {
            float v0 = 0.f, v1 = 0.f;
            if (dx < 3) {
                if (frag == 0) {
                    const int dy = q >> 1;
                    const int ci0 = (q & 1) * 8 + 2 * j;
                    v0 = W[(co * CIN + ci0) * 81 + dt * 27 + dz * 9 + dy * 3 + dx];
                    v1 = W[(co * CIN + ci0 + 1) * 81 + dt * 27 + dz * 9 + dy * 3 + dx];
                } else if (q < 2) {
                    const int ci0 = q * 8 + 2 * j;
                    v0 = W[(co * CIN + ci0) * 81 + dt * 27 + dz * 9 + 6 + dx];
                    v1 = W[(co * CIN + ci0 + 1) * 81 + dt * 27 + dz * 9 + 6 + dx];
                }
            }
            d[j] = pk(v0, v1);
        }
        *(uint4*)(ws + BTAB + (size_t)p * 2048 + frag * 1024 + (size_t)L * 16) =
            make_uint4(d[0], d[1], d[2], d[3]);
    } else if (g < 1280) {
        *(uint4*)(ws + ZOFF + (size_t)(g - 1152) * 16) = make_uint4(0, 0, 0, 0);
    }
}

#define GL16(SRC, DST) __builtin_amdgcn_global_load_lds( \
    (const __attribute__((address_space(1))) unsigned int*)(SRC), \
    (__attribute__((address_space(3))) unsigned int*)(DST), 16, 0, 0)

#define LROW 21
__global__ __launch_bounds__(256, 2) void conv_mfma(
        const char* __restrict__ ws,
        const float* __restrict__ bias,
        float* __restrict__ out) {
    __shared__ char smem[2 * 18 * 2048];   // 73,728 B double buffer (2 blk/CU)
    const int lane = threadIdx.x;
    const int wid  = __builtin_amdgcn_readfirstlane(threadIdx.y);
    // XCD swizzle: z-slab per XCD, t-major order -> halo working set ~2.3MB < L2
    const int bid = blockIdx.x;
    const int xcd = bid & 7, lid = bid >> 3;
    const int z0 = 4 * xcd + (lid & 3);
    const int yq = (lid >> 2) & 3;
    const int t0 = lid >> 4;
    const int y0 = yq * 16;
    const int m = lane & 15, q = lane >> 4, h = q & 1, dyA = q >> 1;
    const int e2 = 2 * m + h;
    const int wid4 = wid * 4;

    f32x4 acc[4][4];
#pragma unroll
    for (int r = 0; r < 4; ++r)
#pragma unroll
        for (int xt = 0; xt < 4; ++xt) acc[r][xt] = (f32x4){0.f, 0.f, 0.f, 0.f};

// Stage plane P into buffer BUF. Wave w, iter k: half-row rw=(w+4k)>>1,
// half=(w+4k)&1 (wave-uniform base + lane*16). OOB rows/planes -> zero row.
#define STAGE(P, BUF) { \
    const int dtS = (P) / 3, dzS = (P) % 3; \
    const int t_in = t0 + dtS - 1, z_in = z0 + dzS - 1; \
    const bool pv = ((unsigned)t_in < TT) && ((unsigned)z_in < ZZ); \
    const int pbase = pv ? (t_in * XT_TB + z_in * XT_ZB) : 0; \
    _Pragma("unroll") \
    for (int k = 0; k < 9; ++k) { \
        const int rw = (wid + 4 * k) >> 1; \
        const int hf = ((wid + 4 * k) & 1) * 1024; \
        const int y_in = y0 - 1 + rw; \
        const bool rv = pv && ((unsigned)y_in < YY); \
        const char* srcS = ws + (rv ? (size_t)(pbase + y_in * XT_YB) : ZOFF) \
                              + hf + lane * 16; \
        GL16(srcS, smem + (BUF) * 36864 + rw * 2048 + hf + lane * 16); \
    } }

// Compute plane P from buffer BUF. fragB k>=16 is zero IN B (no masking).
#define COMPUTE(P, BUF) { \
    const char* bbC = smem + (BUF) * 36864; \
    const short8 BfA = *(const short8*)(ws + BTAB + (P) * 2048 + lane * 16); \
    const short8 BfB = *(const short8*)(ws + BTAB + (P) * 2048 + 1024 + lane * 16); \
    _Pragma("unroll") \
    for (int r = 0; r < 4; ++r) { \
        _Pragma("unroll") \
        for (int xt = 0; xt < 4; ++xt) { \
            const int sw = (32 * xt + e2) * 16; \
            const short8 fa = *(const short8*)(bbC + (wid4 + r + dyA) * 2048 + sw); \
            const short8 fb = *(const short8*)(bbC + (wid4 + r + 2) * 2048 + sw); \
            acc[r][xt] = __builtin_amdgcn_mfma_f32_16x16x32_bf16(fa, BfA, acc[r][xt], 0, 0, 0); \
            acc[r][xt] = __builtin_amdgcn_mfma_f32_16x16x32_bf16(fb, BfB, acc[r][xt], 0, 0, 0); \
        } } }

    // Pipeline: barrier AFTER compute -> stage(P+1) flies under compute(P).
    STAGE(0, 0) __syncthreads();
    STAGE(1, 1) COMPUTE(0, 0) __syncthreads();
    STAGE(2, 0) COMPUTE(1, 1) __syncthreads();
    STAGE(3, 1) COMPUTE(2, 0) __syncthreads();
    STAGE(4, 0) COMPUTE(3, 1) __syncthreads();
    STAGE(5, 1) COMPUTE(4, 0) __syncthreads();
    STAGE(6, 0) COMPUTE(5, 1) __syncthreads();
    STAGE(7, 1) COMPUTE(6, 0) __syncthreads();
    STAGE(8, 0) COMPUTE(7, 1) __syncthreads();
    COMPUTE(8, 0) __syncthreads();
#undef STAGE
#undef COMPUTE

    const float bi0 = bias[0], bi1 = bias[1], bi2 = bias[2], bi3 = bias[3];
    float* swave = (float*)smem + wid * (66 * LROW);   // aliases dead staging
    if (lane < LROW) {
        swave[lane] = 0.f;
        swave[65 * LROW + lane] = 0.f;
    }
    const int colw = lane & 15;
    const int rowq = (lane >> 4) * 4 + 1;
#pragma unroll
    for (int r = 0; r < 4; ++r) {
#pragma unroll
        for (int xt = 0; xt < 4; ++xt)
#pragma unroll
            for (int reg = 0; reg < 4; ++reg)
                swave[(xt * 16 + rowq + reg) * LROW + colw] = acc[r][xt][reg];
        float lg0 = bi0, lg1 = bi1, lg2 = bi2, lg3 = bi3;
#pragma unroll
        for (int dx = 0; dx < 3; ++dx) {
            const float* sp = swave + (lane + dx) * LROW + dx * 4;
            lg0 += sp[0]; lg1 += sp[1]; lg2 += sp[2]; lg3 += sp[3];
        }
        const float mx = fmaxf(fmaxf(lg0, lg1), fmaxf(lg2, lg3));
        const float e0 = __expf(lg0 - mx);
        const float e1 = __expf(lg1 - mx);
        const float e2v = __expf(lg2 - mx);
        const float e3 = __expf(lg3 - mx);
        const float inv = 1.f / (e0 + e1 + e2v + e3);
        const int y = y0 + wid4 + r;
        float* op = out + (size_t)t0 * SX_T + (size_t)z0 * SX_Z + (size_t)y * XX + lane;
        op[0 * (size_t)SX_CI] = e0 * inv;
        op[1 * (size_t)SX_CI] = e1 * inv;
        op[2 * (size_t)SX_CI] = e2v * inv;
        op[3 * (size_t)SX_CI] = e3 * inv;
    }
}

// ================= fallback (R3 vector kernel) if ws too small =================
__global__ __launch_bounds__(256, 4) void conv4d_softmax_vec(
        const float* __restrict__ x, const float* __restrict__ W,
        const float* __restrict__ b, float* __restrict__ out) {
    const int lane = threadIdx.x;
    const int xg = lane & 15, yl = lane >> 4;
    const int y = blockIdx.x * 16 + threadIdx.y * 4 + yl;
    const int z0 = blockIdx.y, t0 = blockIdx.z, x0 = xg * 4;
    float acc[COUT][4];
#pragma unroll
    for (int c = 0; c < COUT; ++c)
#pragma unroll
        for (int xi = 0; xi < 4; ++xi) acc[c][xi] = 0.f;
    for (int ci = 0; ci < CIN; ++ci) {
        const float* xc = x + (size_t)ci * SX_CI;
        const float* wc = W + ci * 81;
#pragma unroll
        for (int dt = 0; dt < 3; ++dt) {
            const int t_in = t0 + dt - 1;
            const int t_c = min(max(t_in, 0), TT - 1);
            const bool tv = (unsigned)t_in < TT;
#pragma unroll
            for (int dz = 0; dz < 3; ++dz) {
                const int z_in = z0 + dz - 1;
                const int z_c = min(max(z_in, 0), ZZ - 1);
                const bool tzvv = tv && ((unsigned)z_in < ZZ);
                const float* plane = xc + (size_t)t_c * SX_T + (size_t)z_c * SX_Z;
                const float* wb = wc + (dt * 3 + dz) * 9;
#pragma unroll
                for (int e = 0; e < 3; ++e) {
                    const int y_in = y + e - 1;
                    const int y_c = min(max(y_in, 0), YY - 1);
                    const bool v = tzvv && ((unsigned)y_in < YY);
                    float4 f = *(const float4*)(plane + y_c * XX + x0);
                    f.x = v ? f.x : 0.f; f.y = v ? f.y : 0.f;
                    f.z = v ? f.z : 0.f; f.w = v ? f.w : 0.f;
                    float hl = __shfl(f.w, (lane - 1) & 63, 64);
                    hl = (xg == 0) ? 0.f : hl;
                    float hr = __shfl(f.x, (lane + 1) & 63, 64);
                    hr = (xg == 15) ? 0.f : hr;
                    const float win[6] = {hl, f.x, f.y, f.z, f.w, hr};
#pragma unroll
                    for (int co = 0; co < COUT; ++co) {
                        const float* wp = wb + co * WCO + e * 3;
                        const float w0 = wp[0], w1 = wp[1], w2 = wp[2];
#pragma unroll
                        for (int xi = 0; xi < 4; ++xi) {
                            float a = acc[co][xi];
                            a = fmaf(win[xi], w0, a);
                            a = fmaf(win[xi + 1], w1, a);
                            a = fmaf(win[xi + 2], w2, a);
                            acc[co][xi] = a;
                        }
                    }
                }
            }
        }
    }
    const float b0 = b[0], b1 = b[1], b2 = b[2], b3 = b[3];
    float4 rr[COUT];
#pragma unroll
    for (int xi = 0; xi < 4; ++xi) {
        const float a0 = acc[0][xi] + b0, a1 = acc[1][xi] + b1;
        const float a2 = acc[2][xi] + b2, a3 = acc[3][xi] + b3;
        const float mm = fmaxf(fmaxf(a0, a1), fmaxf(a2, a3));
        const float e0 = __expf(a0 - mm), e1 = __expf(a1 - mm);
        const float e2 = __expf(a2 - mm), e3 = __expf(a3 - mm);
        const float inv = 1.f / (e0 + e1 + e2 + e3);
        ((float*)&rr[0])[xi] = e0 * inv; ((float*)&rr[1])[xi] = e1 * inv;
        ((float*)&rr[2])[xi] = e2 * inv; ((float*)&rr[3])[xi] = e3 * inv;
    }
    float* op = out + (size_t)t0 * SX_T + (size_t)z0 * SX_Z + (size_t)y * XX + x0;
#pragma unroll
    for (int co = 0; co < COUT; ++co)
        *(float4*)(op + (size_t)co * SX_CI) = rr[co];
}

extern "C" void kernel_launch(void* const* d_in, const int* in_sizes, int n_in,
                              void* d_out, int out_size, void* d_ws, size_t ws_size,
                              hipStream_t stream) {
    const float* x = (const float*)d_in[0];
    const float* W = (const float*)d_in[1];
    const float* b = (const float*)d_in[2];
    float* out = (float*)d_out;

    if (ws_size >= WS_NEED) {
        char* ws = (char*)d_ws;
        transpose_x<<<dim3(4, ZZ, TT), dim3(256), 0, stream>>>(x, ws);
        prep_B<<<dim3(5), dim3(256), 0, stream>>>(W, ws);
        conv_mfma<<<dim3(1280), dim3(64, 4), 0, stream>>>(ws, b, out);
    } else {
        conv4d_softmax_vec<<<dim3(4, ZZ, TT), dim3(64, 4), 0, stream>>>(x, W, b, out);
    }
}